// Round 11
// baseline (291.742 us; speedup 1.0000x reference)
//
#include <hip/hip_runtime.h>
#include <hip/hip_fp16.h>
#include <math.h>

#define NWIN 8

typedef _Float16 f16x8 __attribute__((ext_vector_type(8)));
typedef float f32x4 __attribute__((ext_vector_type(4)));
typedef int i32x4 __attribute__((ext_vector_type(4)));
typedef unsigned int u32x4 __attribute__((ext_vector_type(4)));

__device__ __forceinline__ float eluf(float v) { return v > 0.f ? v : expm1f(v); }

// unpack one u32 (2 x fp16) -> float2
__device__ __forceinline__ float2 cvt2(unsigned int w) {
    __half2 h = *reinterpret_cast<const __half2*>(&w);
    return __half22float2(h);
}

// ---------------- degree count (in-degree) ----------------
__global__ __launch_bounds__(256) void deg_kernel(const int* __restrict__ dst,
                                                  int* __restrict__ counts, int E) {
    int e = blockIdx.x * 256 + threadIdx.x;
    if (e < E) atomicAdd(&counts[dst[e]], 1);
}

// ---------------- bucket alloc + pad fill (x16 buckets) ----------------
__global__ __launch_bounds__(256) void alloc_kernel(const int* __restrict__ counts,
                                                    int* __restrict__ gtotal,
                                                    int* __restrict__ offs,
                                                    int* __restrict__ cursor,
                                                    float* __restrict__ dinv,
                                                    int* __restrict__ csr_src, int n) {
    int i = blockIdx.x * 256 + threadIdx.x;
    if (i >= n) return;
    int c = counts[i];
    int pad = (c + 15) & ~15;            // x16 -> one 16-wide gather iter for deg<=16
    int o = atomicAdd(gtotal, pad);
    offs[i] = o;
    cursor[i] = o;
    dinv[i] = rsqrtf((float)(c + 1));
    for (int j = c; j < pad; ++j) csr_src[o + j] = n;   // dummy -> zero row (hot line)
}

// ---------------- XCD-windowed scatter: window = blockIdx & 7 ----------------
__global__ __launch_bounds__(256) void scatter_kernel(const int* __restrict__ src,
                                                      const int* __restrict__ dst,
                                                      int* __restrict__ cursor,
                                                      int* __restrict__ csr_src,
                                                      int E, int winSize) {
    int win = blockIdx.x & (NWIN - 1);
    int group = blockIdx.x >> 3;
    int nGroups = gridDim.x >> 3;
    int lo = win * winSize, hi = lo + winSize;
    int stride = nGroups * 256;
    for (int e = group * 256 + threadIdx.x; e < E; e += stride) {
        int d = dst[e];
        if (d >= lo && d < hi) {
            int j = atomicAdd(&cursor[d], 1);
            csr_src[j] = src[e];
        }
    }
}

// ---------------- Ts0 = (x[N,128] @ w0[128,64]) * dinv[row], fp16, via MFMA ----------------
__global__ __launch_bounds__(256) void mm128_mfma(const float* __restrict__ H,
                                                  const float* __restrict__ W,
                                                  const float* __restrict__ dinv,
                                                  __half* __restrict__ T, int n, int nTiles) {
    __shared__ _Float16 bhi[4][4][64][8];
    __shared__ _Float16 blo[4][4][64][8];
    int tid = threadIdx.x;
    for (int it = 0; it < 32; ++it) {
        int idx = it * 256 + tid;           // 8192 = 128 k * 64 n
        int k = idx >> 6, nn = idx & 63;
        float w = W[idx];
        _Float16 h = (_Float16)w;
        _Float16 l = (_Float16)(w - (float)h);
        int kt = k >> 5, kr = k & 31;
        int g = kr >> 3, j = kr & 7;
        int ct = nn >> 4, c = nn & 15;
        bhi[kt][ct][g * 16 + c][j] = h;
        blo[kt][ct][g * 16 + c][j] = l;
    }
    if (blockIdx.x == 0 && tid < 64) T[(size_t)n * 64 + tid] = __float2half(0.f);
    __syncthreads();

    int wave = blockIdx.x * 4 + (tid >> 6);
    if (wave >= nTiles) return;
    int lane = tid & 63;
    f16x8 Bh[4][4], Bl[4][4];
    #pragma unroll
    for (int kt = 0; kt < 4; ++kt)
        #pragma unroll
        for (int ct = 0; ct < 4; ++ct) {
            Bh[kt][ct] = *(const f16x8*)&bhi[kt][ct][lane][0];
            Bl[kt][ct] = *(const f16x8*)&blo[kt][ct][lane][0];
        }
    int row0 = wave * 16;
    int arow = row0 + (lane & 15);
    if (arow >= n) arow = n - 1;
    const float* hp = H + (size_t)arow * 128 + ((lane >> 4) << 3);
    f32x4 acc[4];
    #pragma unroll
    for (int ct = 0; ct < 4; ++ct) acc[ct] = (f32x4){0.f, 0.f, 0.f, 0.f};
    #pragma unroll
    for (int kt = 0; kt < 4; ++kt) {
        float4 p0 = *(const float4*)(hp + kt * 32);
        float4 p1 = *(const float4*)(hp + kt * 32 + 4);
        float v[8] = {p0.x, p0.y, p0.z, p0.w, p1.x, p1.y, p1.z, p1.w};
        f16x8 ah, al;
        #pragma unroll
        for (int j = 0; j < 8; ++j) {
            _Float16 h = (_Float16)v[j];
            ah[j] = h;
            al[j] = (_Float16)(v[j] - (float)h);
        }
        #pragma unroll
        for (int ct = 0; ct < 4; ++ct) {
            acc[ct] = __builtin_amdgcn_mfma_f32_16x16x32_f16(ah, Bh[kt][ct], acc[ct], 0, 0, 0);
            acc[ct] = __builtin_amdgcn_mfma_f32_16x16x32_f16(al, Bh[kt][ct], acc[ct], 0, 0, 0);
            acc[ct] = __builtin_amdgcn_mfma_f32_16x16x32_f16(ah, Bl[kt][ct], acc[ct], 0, 0, 0);
        }
    }
    int rbase = row0 + ((lane >> 4) << 2);
    int cbase = lane & 15;
    #pragma unroll
    for (int r = 0; r < 4; ++r) {
        int row = rbase + r;
        if (row < n) {
            float d = dinv[row];
            #pragma unroll
            for (int ct = 0; ct < 4; ++ct)
                T[(size_t)row * 64 + ct * 16 + cbase] = __float2half(acc[ct][r] * d);
        }
    }
}

// 16-wide gather body shared by agg_mm / agg_fc (macro to keep regs local)
#define GATHER16(T4, ax, ay)                                                   \
    {   u32x4 q = T4[(size_t)node * 8 + l8];                                   \
        _Pragma("unroll")                                                      \
        for (int u = 0; u < 4; ++u) {                                          \
            float2 f = cvt2(q[u]);                                             \
            ax[u] += f.x; ax[u + 4] += f.y;                                    \
        }                                                                      \
    }                                                                          \
    int e0 = offs[node];                                                       \
    int e1 = e0 + ((cnt[node] + 15) & ~15);                                    \
    _Pragma("unroll 1")                                                        \
    for (int e = e0; e < e1; e += 16) {                                        \
        i32x4 sa = __builtin_nontemporal_load((const i32x4*)(csr_src + e));    \
        i32x4 sb = __builtin_nontemporal_load((const i32x4*)(csr_src + e + 4));\
        i32x4 sc = __builtin_nontemporal_load((const i32x4*)(csr_src + e + 8));\
        i32x4 sd = __builtin_nontemporal_load((const i32x4*)(csr_src + e + 12));\
        u32x4 q0 = T4[(size_t)sa.x * 8 + l8];                                  \
        u32x4 q1 = T4[(size_t)sa.y * 8 + l8];                                  \
        u32x4 q2 = T4[(size_t)sa.z * 8 + l8];                                  \
        u32x4 q3 = T4[(size_t)sa.w * 8 + l8];                                  \
        u32x4 q4 = T4[(size_t)sb.x * 8 + l8];                                  \
        u32x4 q5 = T4[(size_t)sb.y * 8 + l8];                                  \
        u32x4 q6 = T4[(size_t)sb.z * 8 + l8];                                  \
        u32x4 q7 = T4[(size_t)sb.w * 8 + l8];                                  \
        u32x4 q8 = T4[(size_t)sc.x * 8 + l8];                                  \
        u32x4 q9 = T4[(size_t)sc.y * 8 + l8];                                  \
        u32x4 qa = T4[(size_t)sc.z * 8 + l8];                                  \
        u32x4 qb = T4[(size_t)sc.w * 8 + l8];                                  \
        u32x4 qc = T4[(size_t)sd.x * 8 + l8];                                  \
        u32x4 qd = T4[(size_t)sd.y * 8 + l8];                                  \
        u32x4 qe = T4[(size_t)sd.z * 8 + l8];                                  \
        u32x4 qf = T4[(size_t)sd.w * 8 + l8];                                  \
        _Pragma("unroll")                                                      \
        for (int u = 0; u < 4; ++u) {                                          \
            float2 f0 = cvt2(q0[u]); float2 f1 = cvt2(q1[u]);                  \
            float2 f2 = cvt2(q2[u]); float2 f3 = cvt2(q3[u]);                  \
            float2 f4 = cvt2(q4[u]); float2 f5 = cvt2(q5[u]);                  \
            float2 f6 = cvt2(q6[u]); float2 f7 = cvt2(q7[u]);                  \
            ax[u]     += ((f0.x + f1.x) + (f2.x + f3.x)) + ((f4.x + f5.x) + (f6.x + f7.x)); \
            ax[u + 4] += ((f0.y + f1.y) + (f2.y + f3.y)) + ((f4.y + f5.y) + (f6.y + f7.y)); \
            float2 g0 = cvt2(q8[u]); float2 g1 = cvt2(q9[u]);                  \
            float2 g2 = cvt2(qa[u]); float2 g3 = cvt2(qb[u]);                  \
            float2 g4 = cvt2(qc[u]); float2 g5 = cvt2(qd[u]);                  \
            float2 g6 = cvt2(qe[u]); float2 g7 = cvt2(qf[u]);                  \
            ay[u]     += ((g0.x + g1.x) + (g2.x + g3.x)) + ((g4.x + g5.x) + (g6.x + g7.x)); \
            ay[u + 4] += ((g0.y + g1.y) + (g2.y + g3.y)) + ((g4.y + g5.y) + (g6.y + g7.y)); \
        }                                                                      \
    }

// ---------------- fused agg + next-layer MFMA matmul ----------------
// Block = 512 threads = 64 nodes. Gather: 8-lane group per node, lane loads
// 16 B; 16-edge iterations -> 128 rows in flight per wave; deg<=16 = 1 iter.
__global__ __launch_bounds__(512, 5) void agg_mm(const __half* __restrict__ T,
                                                 const int* __restrict__ offs,
                                                 const int* __restrict__ cnt,
                                                 const int* __restrict__ csr_src,
                                                 const float* __restrict__ dinv,
                                                 const float* __restrict__ bias,
                                                 const float* __restrict__ Wn,
                                                 __half* __restrict__ out, int n) {
    __shared__ _Float16 bhi[2][4][64][8];   // 8 KB
    __shared__ _Float16 blo[2][4][64][8];   // 8 KB
    __shared__ float rowbuf[64][68];        // 17.4 KB
    int tid = threadIdx.x;
    for (int it = 0; it < 8; ++it) {
        int idx = it * 512 + tid;           // 4096 = 64 k * 64 n
        int k = idx >> 6, nn = idx & 63;
        float w = Wn[idx];
        _Float16 h = (_Float16)w;
        _Float16 lo = (_Float16)(w - (float)h);
        int kt = k >> 5, kr = k & 31;
        int g = kr >> 3, j = kr & 7;
        int ct = nn >> 4, c = nn & 15;
        bhi[kt][ct][g * 16 + c][j] = h;
        blo[kt][ct][g * 16 + c][j] = lo;
    }
    if (blockIdx.x == 0 && tid < 64) out[(size_t)n * 64 + tid] = __float2half(0.f);

    int grp = tid >> 3;          // local node 0..63
    int l8 = tid & 7;            // 16B slice of the row
    int node = blockIdx.x * 64 + grp;
    float hA[4] = {0.f, 0.f, 0.f, 0.f};
    float hB[4] = {0.f, 0.f, 0.f, 0.f};
    if (node < n) {
        const u32x4* T4 = (const u32x4*)T;
        float ax[8] = {0,0,0,0,0,0,0,0};
        float ay[8] = {0,0,0,0,0,0,0,0};
        GATHER16(T4, ax, ay)
        float di = dinv[node];
        float4 b0 = *(const float4*)(bias + l8 * 8);
        float4 b1 = *(const float4*)(bias + l8 * 8 + 4);
        float bb[8] = {b0.x, b0.y, b0.z, b0.w, b1.x, b1.y, b1.z, b1.w};
        #pragma unroll
        for (int u = 0; u < 4; ++u) {
            hA[u] = eluf((ax[u] + ay[u]) * di + bb[2 * u]);
            hB[u] = eluf((ax[u + 4] + ay[u + 4]) * di + bb[2 * u + 1]);
        }
    }
    float4 r0 = make_float4(hA[0], hB[0], hA[1], hB[1]);
    float4 r1 = make_float4(hA[2], hB[2], hA[3], hB[3]);
    *(float4*)&rowbuf[grp][l8 * 8] = r0;
    *(float4*)&rowbuf[grp][l8 * 8 + 4] = r1;
    __syncthreads();

    // MFMA phase: wave wv -> row-tile (wv>>1), col-half (wv&1)
    int wv = tid >> 6, lane = tid & 63;
    int tile = wv >> 1, ct0 = (wv & 1) * 2;
    f16x8 Bh[2][2], Bl[2][2];
    #pragma unroll
    for (int kt = 0; kt < 2; ++kt)
        #pragma unroll
        for (int c2 = 0; c2 < 2; ++c2) {
            Bh[kt][c2] = *(const f16x8*)&bhi[kt][ct0 + c2][lane][0];
            Bl[kt][c2] = *(const f16x8*)&blo[kt][ct0 + c2][lane][0];
        }
    int trow = tile * 16 + (lane & 15);
    int kb = (lane >> 4) << 3;
    f32x4 acc[2] = {(f32x4){0.f,0.f,0.f,0.f}, (f32x4){0.f,0.f,0.f,0.f}};
    #pragma unroll
    for (int kt = 0; kt < 2; ++kt) {
        float4 p0 = *(const float4*)&rowbuf[trow][kt * 32 + kb];
        float4 p1 = *(const float4*)&rowbuf[trow][kt * 32 + kb + 4];
        float v[8] = {p0.x, p0.y, p0.z, p0.w, p1.x, p1.y, p1.z, p1.w};
        f16x8 ah, al;
        #pragma unroll
        for (int j = 0; j < 8; ++j) {
            _Float16 h = (_Float16)v[j];
            ah[j] = h;
            al[j] = (_Float16)(v[j] - (float)h);
        }
        #pragma unroll
        for (int c2 = 0; c2 < 2; ++c2) {
            acc[c2] = __builtin_amdgcn_mfma_f32_16x16x32_f16(ah, Bh[kt][c2], acc[c2], 0, 0, 0);
            acc[c2] = __builtin_amdgcn_mfma_f32_16x16x32_f16(al, Bh[kt][c2], acc[c2], 0, 0, 0);
            acc[c2] = __builtin_amdgcn_mfma_f32_16x16x32_f16(ah, Bl[kt][c2], acc[c2], 0, 0, 0);
        }
    }
    int rb = tile * 16 + ((lane >> 4) << 2);
    int cb = lane & 15;
    #pragma unroll
    for (int r = 0; r < 4; ++r) {
        int node2 = blockIdx.x * 64 + rb + r;
        if (node2 < n) {
            float d = dinv[node2];
            #pragma unroll
            for (int c2 = 0; c2 < 2; ++c2)
                out[(size_t)node2 * 64 + (ct0 + c2) * 16 + cb] =
                    __float2half(acc[c2][r] * d);
        }
    }
}

// ---------------- fused final: agg + ELU + FC(64->16) MFMA + softmax ----------------
__global__ __launch_bounds__(512, 5) void agg_fc(const __half* __restrict__ T,
                                                 const int* __restrict__ offs,
                                                 const int* __restrict__ cnt,
                                                 const int* __restrict__ csr_src,
                                                 const float* __restrict__ dinv,
                                                 const float* __restrict__ bias,
                                                 const float* __restrict__ fcw,
                                                 const float* __restrict__ fcb,
                                                 float* __restrict__ out, int n) {
    __shared__ _Float16 bhi[2][64][8];      // 2 KB
    __shared__ _Float16 blo[2][64][8];
    __shared__ float rowbuf[64][68];
    int tid = threadIdx.x;
    for (int it = 0; it < 2; ++it) {
        int idx = it * 512 + tid;           // 1024 = 64 k * 16 j
        int k = idx >> 4, j16 = idx & 15;
        float w = fcw[idx];
        _Float16 h = (_Float16)w;
        _Float16 lo = (_Float16)(w - (float)h);
        int kt = k >> 5, kr = k & 31;
        int g = kr >> 3, j = kr & 7;
        bhi[kt][g * 16 + j16][j] = h;
        blo[kt][g * 16 + j16][j] = lo;
    }
    int grp = tid >> 3, l8 = tid & 7;
    int node = blockIdx.x * 64 + grp;
    float hA[4] = {0.f, 0.f, 0.f, 0.f};
    float hB[4] = {0.f, 0.f, 0.f, 0.f};
    if (node < n) {
        const u32x4* T4 = (const u32x4*)T;
        float ax[8] = {0,0,0,0,0,0,0,0};
        float ay[8] = {0,0,0,0,0,0,0,0};
        GATHER16(T4, ax, ay)
        float di = dinv[node];
        float4 b0 = *(const float4*)(bias + l8 * 8);
        float4 b1 = *(const float4*)(bias + l8 * 8 + 4);
        float bb[8] = {b0.x, b0.y, b0.z, b0.w, b1.x, b1.y, b1.z, b1.w};
        #pragma unroll
        for (int u = 0; u < 4; ++u) {
            hA[u] = eluf((ax[u] + ay[u]) * di + bb[2 * u]);
            hB[u] = eluf((ax[u + 4] + ay[u + 4]) * di + bb[2 * u + 1]);
        }
    }
    float4 r0 = make_float4(hA[0], hB[0], hA[1], hB[1]);
    float4 r1 = make_float4(hA[2], hB[2], hA[3], hB[3]);
    *(float4*)&rowbuf[grp][l8 * 8] = r0;
    *(float4*)&rowbuf[grp][l8 * 8 + 4] = r1;
    __syncthreads();

    int wv = tid >> 6, lane = tid & 63;
    if (wv >= 4) return;                    // 4 waves cover the 4 row-tiles
    f16x8 Bh[2], Bl[2];
    #pragma unroll
    for (int kt = 0; kt < 2; ++kt) {
        Bh[kt] = *(const f16x8*)&bhi[kt][lane][0];
        Bl[kt] = *(const f16x8*)&blo[kt][lane][0];
    }
    int trow = wv * 16 + (lane & 15);
    int kb = (lane >> 4) << 3;
    f32x4 acc = (f32x4){0.f, 0.f, 0.f, 0.f};
    #pragma unroll
    for (int kt = 0; kt < 2; ++kt) {
        float4 p0 = *(const float4*)&rowbuf[trow][kt * 32 + kb];
        float4 p1 = *(const float4*)&rowbuf[trow][kt * 32 + kb + 4];
        float v[8] = {p0.x, p0.y, p0.z, p0.w, p1.x, p1.y, p1.z, p1.w};
        f16x8 ah, al;
        #pragma unroll
        for (int j = 0; j < 8; ++j) {
            _Float16 h = (_Float16)v[j];
            ah[j] = h;
            al[j] = (_Float16)(v[j] - (float)h);
        }
        acc = __builtin_amdgcn_mfma_f32_16x16x32_f16(ah, Bh[kt], acc, 0, 0, 0);
        acc = __builtin_amdgcn_mfma_f32_16x16x32_f16(al, Bh[kt], acc, 0, 0, 0);
        acc = __builtin_amdgcn_mfma_f32_16x16x32_f16(ah, Bl[kt], acc, 0, 0, 0);
    }
    float bj = fcb[lane & 15];
    #pragma unroll
    for (int r = 0; r < 4; ++r) {
        float o = acc[r] + bj;
        float m = o;
        #pragma unroll
        for (int d = 8; d; d >>= 1) m = fmaxf(m, __shfl_xor(m, d, 64));
        float ex = expf(o - m);
        float s = ex;
        #pragma unroll
        for (int d = 8; d; d >>= 1) s += __shfl_xor(s, d, 64);
        int node2 = blockIdx.x * 64 + wv * 16 + ((lane >> 4) << 2) + r;
        if (node2 < n) out[(size_t)node2 * 16 + (lane & 15)] = ex / s;
    }
}

extern "C" void kernel_launch(void* const* d_in, const int* in_sizes, int n_in,
                              void* d_out, int out_size, void* d_ws, size_t ws_size,
                              hipStream_t stream) {
    const float* x   = (const float*)d_in[0];
    const int*   ei  = (const int*)d_in[1];
    const float* w0  = (const float*)d_in[2];
    const float* b0  = (const float*)d_in[3];
    const float* w1  = (const float*)d_in[4];
    const float* b1  = (const float*)d_in[5];
    const float* w2  = (const float*)d_in[6];
    const float* b2  = (const float*)d_in[7];
    const float* fcw = (const float*)d_in[8];
    const float* fcb = (const float*)d_in[9];
    float* out = (float*)d_out;

    const int N = in_sizes[0] / 128;
    const int E = in_sizes[1] / 2;
    const int* src = ei;
    const int* dst = ei + E;
    const int csr_cap = E + 16 * N + 16;

    char* p = (char*)d_ws;
    auto take = [&](size_t bytes) {
        char* q = p;
        p += (bytes + 255) & ~(size_t)255;
        return q;
    };
    int*    counts  = (int*)take((size_t)(N + 1) * 4);  // counts[N] = gtotal
    int*    gtotal  = counts + N;
    int*    offs    = (int*)take((size_t)N * 4);
    int*    cursor  = (int*)take((size_t)N * 4);
    float*  dinv    = (float*)take((size_t)N * 4);
    int*    csr_src = (int*)take((size_t)csr_cap * 4);
    __half* tbufA   = (__half*)take((size_t)(N + 1) * 64 * 2);
    __half* tbufB   = (__half*)take((size_t)(N + 1) * 64 * 2);

    hipMemsetAsync(counts, 0, (size_t)(N + 1) * 4, stream);

    deg_kernel<<<(E + 255) / 256, 256, 0, stream>>>(dst, counts, E);
    alloc_kernel<<<(N + 255) / 256, 256, 0, stream>>>(counts, gtotal, offs, cursor,
                                                      dinv, csr_src, N);
    int winSize = (N + NWIN - 1) / NWIN;
    scatter_kernel<<<1024, 256, 0, stream>>>(src, dst, cursor, csr_src, E, winSize);

    int nTiles = (N + 15) / 16;
    int agg_grid = (N + 63) / 64;

    mm128_mfma<<<(nTiles + 3) / 4, 256, 0, stream>>>(x, w0, dinv, tbufA, N, nTiles);
    agg_mm<<<agg_grid, 512, 0, stream>>>(tbufA, offs, counts, csr_src,
                                         dinv, b0, w1, tbufB, N);
    agg_mm<<<agg_grid, 512, 0, stream>>>(tbufB, offs, counts, csr_src,
                                         dinv, b1, w2, tbufA, N);
    agg_fc<<<agg_grid, 512, 0, stream>>>(tbufA, offs, counts, csr_src,
                                         dinv, b2, fcw, fcb, out, N);
}